// Round 2
// baseline (3132.727 us; speedup 1.0000x reference)
//
#include <hip/hip_runtime.h>
#include <hip/hip_bf16.h>
#include <cstdint>
#include <cstddef>

typedef __hip_bfloat16 bf16;
typedef short bf16x8 __attribute__((ext_vector_type(8)));   // 8 bf16 (4 VGPRs)
typedef float f32x4 __attribute__((ext_vector_type(4)));

#define SQRT_E   27.712812921102035f   // sqrt(768)
#define ASCALE   (0.05f * 27.712812921102035f)
#define NTOK     3152                  // B * (N+1) = 16*197
#define MPAD     3200                  // padded to 25 * 128

__device__ __forceinline__ void load_lds16(const bf16* g, bf16* l) {
    __builtin_amdgcn_global_load_lds(
        (const __attribute__((address_space(1))) void*)g,
        (__attribute__((address_space(3))) void*)l, 16, 0, 0);
}

__device__ __forceinline__ float block_sum(float v, float* sbuf) {
#pragma unroll
    for (int m = 32; m >= 1; m >>= 1) v += __shfl_xor(v, m);
    __syncthreads();                       // protect sbuf reuse across calls
    if ((threadIdx.x & 63) == 0) sbuf[threadIdx.x >> 6] = v;
    __syncthreads();
    return sbuf[0] + sbuf[1] + sbuf[2] + sbuf[3];
}

// ---------------- im2col: x f32 [16,3,224,224] -> Apatch bf16 [3200][768] -----
__global__ __launch_bounds__(256) void im2col_kernel(const float* __restrict__ x,
                                                     bf16* __restrict__ A) {
    int idx = blockIdx.x * 256 + threadIdx.x;          // < 3200*768
    int row = idx / 768, col = idx - row * 768;
    if (row >= 3136) { A[idx] = __float2bfloat16(0.f); return; }
    int b = row / 196, pp = row - b * 196;
    int gy = pp / 14, gx = pp - gy * 14;
    int c = col >> 8, rem = col & 255, py = rem >> 4, px = rem & 15;
    A[idx] = __float2bfloat16(
        x[((size_t)(b * 3 + c) * 224 + gy * 16 + py) * 224 + gx * 16 + px]);
}

// ---------------- assemble h from tproj + cls + pos ---------------------------
__global__ __launch_bounds__(256) void assemble_kernel(
    const float* __restrict__ tproj, const float* __restrict__ pb,
    const float* __restrict__ cls, const float* __restrict__ pos,
    float* __restrict__ h, bf16* __restrict__ hb) {
    int row = blockIdx.x;                 // 0..3151
    int b = row / 197, n = row - b * 197;
#pragma unroll
    for (int i = 0; i < 3; i++) {
        int c = threadIdx.x + i * 256;
        float v;
        if (n == 0) v = cls[c] + pos[c];
        else v = tproj[(size_t)(b * 196 + n - 1) * 768 + c] + pb[c] + pos[(size_t)n * 768 + c];
        h[(size_t)row * 768 + c] = v;
        hb[(size_t)row * 768 + c] = __float2bfloat16(v);
    }
}

// ---------------- bf16 GEMM: C = A @ W^T, W f32 converted during staging ------
// grid.x = nSegs*tilesPerSeg (seg picks B0/B1/B2, C col offset seg*segColStride)
// grid.y = M/128 ; grid.z = split-K part (A,B += z*Klen ; C += z*partStride)
__global__ __launch_bounds__(256) void gemm_bt(
    const bf16* __restrict__ A, int lda,
    const float* __restrict__ B0, const float* __restrict__ B1, const float* __restrict__ B2,
    int tilesPerSeg, int segColStride,
    float* __restrict__ C, int ldc, long long partStride,
    int Klen, int ldb) {
    __shared__ __align__(16) bf16 As[128 * 32];
    __shared__ __align__(16) bf16 Bs[128 * 32];
    const int tid = threadIdx.x;
    const int lane = tid & 63, wave = tid >> 6;
    const int wm = wave & 1, wn = wave >> 1;
    const int quad = lane >> 4, l16 = lane & 15;
    const int seg = blockIdx.x / tilesPerSeg;
    const int nt = blockIdx.x - seg * tilesPerSeg;
    const float* B = (seg == 0) ? B0 : (seg == 1 ? B1 : B2);
    const int row0 = blockIdx.y * 128;
    const int col0 = nt * 128;
    const long long kofs = (long long)blockIdx.z * Klen;
    const bf16* Ab = A + (size_t)row0 * lda + kofs;
    const float* Bb = B + (size_t)col0 * ldb + kofs;
    float* Cb = C + (long long)blockIdx.z * partStride + (long long)seg * segColStride;

    f32x4 acc[4][4];
    f32x4 zero = {0.f, 0.f, 0.f, 0.f};
#pragma unroll
    for (int i = 0; i < 4; i++)
#pragma unroll
        for (int j = 0; j < 4; j++) acc[i][j] = zero;

    for (int k0 = 0; k0 < Klen; k0 += 32) {
#pragma unroll
        for (int it = 0; it < 2; ++it) {              // A: async 16B global->LDS
            int cidx = it * 256 + tid;
            int r = cidx >> 2, cg = cidx & 3;
            load_lds16(Ab + (size_t)r * lda + k0 + cg * 8, As + cidx * 8);
        }
#pragma unroll
        for (int it = 0; it < 2; ++it) {              // B: f32 load, cvt, 16B LDS store
            int cidx = it * 256 + tid;
            int r = cidx >> 2, cg = cidx & 3;
            const float* bs = Bb + (size_t)r * ldb + k0 + cg * 8;
            float4 f0 = *(const float4*)bs;
            float4 f1 = *(const float4*)(bs + 4);
            bf16 tmp[8];
            tmp[0] = __float2bfloat16(f0.x); tmp[1] = __float2bfloat16(f0.y);
            tmp[2] = __float2bfloat16(f0.z); tmp[3] = __float2bfloat16(f0.w);
            tmp[4] = __float2bfloat16(f1.x); tmp[5] = __float2bfloat16(f1.y);
            tmp[6] = __float2bfloat16(f1.z); tmp[7] = __float2bfloat16(f1.w);
            *reinterpret_cast<uint4*>(Bs + cidx * 8) = *reinterpret_cast<const uint4*>(tmp);
        }
        __syncthreads();
        bf16x8 av[4], bv[4];
#pragma unroll
        for (int i = 0; i < 4; i++) {
            av[i] = *(const bf16x8*)(As + (wm * 64 + i * 16 + l16) * 32 + quad * 8);
            bv[i] = *(const bf16x8*)(Bs + (wn * 64 + i * 16 + l16) * 32 + quad * 8);
        }
#pragma unroll
        for (int i = 0; i < 4; i++)
#pragma unroll
            for (int j = 0; j < 4; j++)
                acc[i][j] = __builtin_amdgcn_mfma_f32_16x16x32_bf16(av[i], bv[j], acc[i][j], 0, 0, 0);
        __syncthreads();
    }
#pragma unroll
    for (int i = 0; i < 4; i++) {
        int rr = row0 + wm * 64 + i * 16 + quad * 4;
#pragma unroll
        for (int j = 0; j < 4; j++) {
            int cc = col0 + wn * 64 + j * 16 + l16;
#pragma unroll
            for (int r = 0; r < 4; r++)
                Cb[(size_t)(rr + r) * ldc + cc] = acc[i][j][r];
        }
    }
}

// ---------------- q/k cosine-norm + scale, build Q,K,VT bf16 ------------------
// Q,K: [192][208][64]; VT: [192][64][224]; pads zeroed.
__global__ __launch_bounds__(256) void qk_norm_kernel(
    const float* __restrict__ qkv, const float* __restrict__ s_l,
    bf16* __restrict__ Q, bf16* __restrict__ K, bf16* __restrict__ VT) {
    int gw = blockIdx.x * 4 + (threadIdx.x >> 6);   // < 16*224*12
    int lane = threadIdx.x & 63;
    int h = gw % 12;
    int n = (gw / 12) % 224;
    int b = gw / (12 * 224);
    int bh = b * 12 + h;
    bf16 z = __float2bfloat16(0.f);
    if (n >= 208) { VT[((size_t)bh * 64 + lane) * 224 + n] = z; return; }
    if (n >= 197) {
        Q[((size_t)bh * 208 + n) * 64 + lane] = z;
        K[((size_t)bh * 208 + n) * 64 + lane] = z;
        VT[((size_t)bh * 64 + lane) * 224 + n] = z;
        return;
    }
    size_t row = (size_t)(b * 197 + n) * 2304;
    float q = qkv[row + h * 64 + lane];
    float k = qkv[row + 768 + h * 64 + lane];
    float v = qkv[row + 1536 + h * 64 + lane];
    float qs = q * q, ks = k * k;
#pragma unroll
    for (int m = 32; m >= 1; m >>= 1) { qs += __shfl_xor(qs, m); ks += __shfl_xor(ks, m); }
    float s = s_l[h * 64 + lane] * SQRT_E;
    float qn = q / fmaxf(sqrtf(qs), 1e-6f) * s;
    float kn = k / fmaxf(sqrtf(ks), 1e-6f) * s;
    Q[((size_t)bh * 208 + n) * 64 + lane] = __float2bfloat16(qn);
    K[((size_t)bh * 208 + n) * 64 + lane] = __float2bfloat16(kn);
    VT[((size_t)bh * 64 + lane) * 224 + n] = __float2bfloat16(v);
}

// ---------------- attention: one wave per (b,h,q-tile) ------------------------
__global__ __launch_bounds__(64) void attn_kernel(
    const bf16* __restrict__ Q, const bf16* __restrict__ K,
    const bf16* __restrict__ VT, bf16* __restrict__ O) {
    __shared__ __align__(16) bf16 Ps[16 * 224];
    int lane = threadIdx.x;
    int quad = lane >> 4, l16 = lane & 15;
    int bh = blockIdx.x % 192;            // same bh -> same XCD residue (192%8==0)
    int qt = blockIdx.x / 192;            // 0..12
    int b = bh / 12, h = bh - b * 12;
    const bf16* Qb = Q + (size_t)bh * 208 * 64;
    const bf16* Kb = K + (size_t)bh * 208 * 64;
    const bf16* Vb = VT + (size_t)bh * 64 * 224;
    f32x4 zero = {0.f, 0.f, 0.f, 0.f};

    bf16x8 a0 = *(const bf16x8*)(Qb + (qt * 16 + l16) * 64 + quad * 8);
    bf16x8 a1 = *(const bf16x8*)(Qb + (qt * 16 + l16) * 64 + quad * 8 + 32);

    f32x4 lg[13];
#pragma unroll
    for (int kt = 0; kt < 13; kt++) {
        bf16x8 b0 = *(const bf16x8*)(Kb + (kt * 16 + l16) * 64 + quad * 8);
        bf16x8 b1 = *(const bf16x8*)(Kb + (kt * 16 + l16) * 64 + quad * 8 + 32);
        f32x4 c = zero;
        c = __builtin_amdgcn_mfma_f32_16x16x32_bf16(a0, b0, c, 0, 0, 0);
        c = __builtin_amdgcn_mfma_f32_16x16x32_bf16(a1, b1, c, 0, 0, 0);
        lg[kt] = c;
    }
    float mx[4] = {-3e38f, -3e38f, -3e38f, -3e38f};
#pragma unroll
    for (int kt = 0; kt < 13; kt++) {
        bool valid = (kt * 16 + l16) < 197;
#pragma unroll
        for (int r = 0; r < 4; r++) {
            float v = valid ? lg[kt][r] * 8.0f : -3e38f;   // * sqrt(HD)
            lg[kt][r] = v;
            mx[r] = fmaxf(mx[r], v);
        }
    }
#pragma unroll
    for (int m = 1; m < 16; m <<= 1)
#pragma unroll
        for (int r = 0; r < 4; r++) mx[r] = fmaxf(mx[r], __shfl_xor(mx[r], m));
    float sm[4] = {0.f, 0.f, 0.f, 0.f};
#pragma unroll
    for (int kt = 0; kt < 13; kt++)
#pragma unroll
        for (int r = 0; r < 4; r++) {
            float p = __expf(lg[kt][r] - mx[r]);
            lg[kt][r] = p;
            sm[r] += p;
        }
#pragma unroll
    for (int m = 1; m < 16; m <<= 1)
#pragma unroll
        for (int r = 0; r < 4; r++) sm[r] += __shfl_xor(sm[r], m);
    float inv[4];
#pragma unroll
    for (int r = 0; r < 4; r++) inv[r] = 1.f / sm[r];
    // P (C-layout) -> LDS row-major [16][224] for A-layout reload
#pragma unroll
    for (int kt = 0; kt < 13; kt++)
#pragma unroll
        for (int r = 0; r < 4; r++)
            Ps[(quad * 4 + r) * 224 + kt * 16 + l16] = __float2bfloat16(lg[kt][r] * inv[r]);
#pragma unroll
    for (int r = 0; r < 4; r++)
        Ps[(quad * 4 + r) * 224 + 208 + l16] = __float2bfloat16(0.f);
    __syncthreads();
#pragma unroll
    for (int nt = 0; nt < 4; nt++) {
        f32x4 o = zero;
#pragma unroll
        for (int ks = 0; ks < 7; ks++) {
            bf16x8 pa = *(const bf16x8*)(Ps + l16 * 224 + ks * 32 + quad * 8);
            bf16x8 vb = *(const bf16x8*)(Vb + (nt * 16 + l16) * 224 + ks * 32 + quad * 8);
            o = __builtin_amdgcn_mfma_f32_16x16x32_bf16(pa, vb, o, 0, 0, 0);
        }
#pragma unroll
        for (int r = 0; r < 4; r++) {
            int tok = qt * 16 + quad * 4 + r;
            if (tok < 197)
                O[(size_t)(b * 197 + tok) * 768 + h * 64 + nt * 16 + l16] = __float2bfloat16(o[r]);
        }
    }
}

// ---------------- residual + cosine norms (sums split-K partials) -------------
__global__ __launch_bounds__(256) void residual_cos(
    const float* __restrict__ proj, int nParts, long long partStride,
    const float* __restrict__ alpha,
    float* __restrict__ h, bf16* __restrict__ hb) {
    __shared__ float sbuf[4];
    int row = blockIdx.x, tid = threadIdx.x;
    float p[3];
    float ss = 0.f;
#pragma unroll
    for (int i = 0; i < 3; i++) {
        int c = tid + i * 256;
        float v = 0.f;
        for (int pt = 0; pt < nParts; pt++) v += proj[(long long)pt * partStride + (size_t)row * 768 + c];
        p[i] = v;
        ss += v * v;
    }
    ss = block_sum(ss, sbuf);
    float inv1 = 1.f / fmaxf(sqrtf(ss), 1e-6f);
    float ss2 = 0.f;
#pragma unroll
    for (int i = 0; i < 3; i++) {
        int c = tid + i * 256;
        float hv = h[(size_t)row * 768 + c];
        float a = alpha[c] * ASCALE;
        float m = hv + a * (p[i] * inv1 - hv);
        p[i] = m;
        ss2 += m * m;
    }
    ss2 = block_sum(ss2, sbuf);
    float inv2 = 1.f / fmaxf(sqrtf(ss2), 1e-6f);
#pragma unroll
    for (int i = 0; i < 3; i++) {
        int c = tid + i * 256;
        float v = p[i] * inv2;
        h[(size_t)row * 768 + c] = v;
        hb[(size_t)row * 768 + c] = __float2bfloat16(v);
    }
}

// ---------------- SwiGLU: ug f32 [3200][6144] -> hidden bf16 [3200][3072] -----
__global__ __launch_bounds__(256) void swiglu_kernel(
    const float* __restrict__ ug, const float* __restrict__ su,
    const float* __restrict__ sv, bf16* __restrict__ hidden) {
    int idx = blockIdx.x * 256 + threadIdx.x;          // < 3152*3072
    int row = idx / 3072, c = idx - row * 3072;
    float u = ug[(size_t)row * 6144 + c] * su[c];
    float v = ug[(size_t)row * 6144 + 3072 + c] * sv[c] * SQRT_E;
    float sig = 1.f / (1.f + __expf(-v));
    hidden[(size_t)row * 3072 + c] = __float2bfloat16(u * v * sig);
}

// ---------------- layernorm of tokens 1..196 -> d_out (f32) -------------------
__global__ __launch_bounds__(256) void layernorm_out(
    const float* __restrict__ h, const float* __restrict__ w,
    const float* __restrict__ bia, float* __restrict__ out) {
    __shared__ float sbuf[4];
    int bi = blockIdx.x;                   // 0..3135
    int b = bi / 196, j = bi - b * 196;
    int row = b * 197 + j + 1;
    int tid = threadIdx.x;
    float xv[3];
    float s = 0.f;
#pragma unroll
    for (int i = 0; i < 3; i++) {
        xv[i] = h[(size_t)row * 768 + tid + i * 256];
        s += xv[i];
    }
    s = block_sum(s, sbuf);
    float mean = s * (1.f / 768.f);
    float s2 = 0.f;
#pragma unroll
    for (int i = 0; i < 3; i++) { float d = xv[i] - mean; s2 += d * d; }
    s2 = block_sum(s2, sbuf);
    float var = s2 * (1.f / 768.f);
    float invs = 1.f / sqrtf(var + 1e-6f);
#pragma unroll
    for (int i = 0; i < 3; i++) {
        int c = tid + i * 256;
        out[(size_t)bi * 768 + c] = (xv[i] - mean) * invs * w[c] + bia[c];
    }
}

extern "C" void kernel_launch(void* const* d_in, const int* in_sizes, int n_in,
                              void* d_out, int out_size, void* d_ws, size_t ws_size,
                              hipStream_t stream) {
    (void)in_sizes; (void)n_in; (void)out_size; (void)ws_size;
    const float* x      = (const float*)d_in[0];
    const float* patchw = (const float*)d_in[1];
    const float* patchb = (const float*)d_in[2];
    const float* cls    = (const float*)d_in[3];
    const float* pos    = (const float*)d_in[4];
    const float* Wq     = (const float*)d_in[5];
    const float* Wk     = (const float*)d_in[6];
    const float* Wv     = (const float*)d_in[7];
    const float* Wo     = (const float*)d_in[8];
    const float* s_qk   = (const float*)d_in[9];
    const float* Wup    = (const float*)d_in[10];
    const float* Wgate  = (const float*)d_in[11];
    const float* Wdown  = (const float*)d_in[12];
    const float* s_u    = (const float*)d_in[13];
    const float* s_v    = (const float*)d_in[14];
    const float* alA    = (const float*)d_in[15];
    const float* alM    = (const float*)d_in[16];
    const float* fcw    = (const float*)d_in[17];
    const float* fcb    = (const float*)d_in[18];
    float* out = (float*)d_out;

    char* ws = (char*)d_ws;
    size_t ofs = 0;
    auto alloc = [&](size_t bytes) -> void* {
        void* p = ws + ofs;
        ofs += (bytes + 255) & ~(size_t)255;
        return p;
    };
    // ws budget ~118 MB via aliasing (lifetimes verified disjoint):
    float* h      = (float*)alloc((size_t)MPAD * 768 * 4);    //  9.8 MB
    float* ug     = (float*)alloc((size_t)MPAD * 6144 * 4);   // 78.6 MB: tproj | qkv+Q+K+VT | partials | up/gate
    bf16*  hb     = (bf16*)alloc((size_t)MPAD * 768 * 2);     //  4.9 MB
    bf16*  attno  = (bf16*)alloc((size_t)MPAD * 768 * 2);     //  4.9 MB
    bf16*  hidden = (bf16*)alloc((size_t)MPAD * 3072 * 2);    // 19.7 MB (also Apatch)

    float* qkv   = ug;                              // 3200*2304 f32
    bf16*  Qb    = (bf16*)(ug + 7372800);           // 192*208*64
    bf16*  Kb    = Qb + 2555904;
    bf16*  VTb   = Kb + 2555904;                    // 192*64*224
    bf16*  Apatch = hidden;
    float* tproj  = ug;

    const long long PSTR = (long long)MPAD * 768;   // split-K partial stride (f32 elems)
    const size_t EE = 768 * 768, FE = (size_t)3072 * 768;

    // ---- patch embed ----
    im2col_kernel<<<9600, 256, 0, stream>>>(x, Apatch);
    gemm_bt<<<dim3(6, 25, 1), 256, 0, stream>>>(Apatch, 768, patchw, patchw, patchw,
                                                6, 0, tproj, 768, 0, 768, 768);
    assemble_kernel<<<3152, 256, 0, stream>>>(tproj, patchb, cls, pos, h, hb);

    for (int l = 0; l < 12; l++) {
        const float* wq = Wq + (size_t)l * EE;
        const float* wk = Wk + (size_t)l * EE;
        const float* wv = Wv + (size_t)l * EE;
        const float* wo = Wo + (size_t)l * EE;
        const float* wu = Wup + (size_t)l * FE;
        const float* wg = Wgate + (size_t)l * FE;
        const float* wd = Wdown + (size_t)l * FE;

        // QKV (fused 3-segment GEMM)
        gemm_bt<<<dim3(18, 25, 1), 256, 0, stream>>>(hb, 768, wq, wk, wv,
                                                     6, 768, qkv, 2304, 0, 768, 768);
        qk_norm_kernel<<<10752, 256, 0, stream>>>(qkv, s_qk + (size_t)l * 768, Qb, Kb, VTb);
        attn_kernel<<<2496, 64, 0, stream>>>(Qb, Kb, VTb, attno);
        // O-proj, split-K = 2
        gemm_bt<<<dim3(6, 25, 2), 256, 0, stream>>>(attno, 768, wo, wo, wo,
                                                    6, 0, ug, 768, PSTR, 384, 768);
        residual_cos<<<3152, 256, 0, stream>>>(ug, 2, PSTR, alA + (size_t)l * 768, h, hb);
        // up + gate (fused 2-segment GEMM)
        gemm_bt<<<dim3(48, 25, 1), 256, 0, stream>>>(hb, 768, wu, wg, wg,
                                                     24, 3072, ug, 6144, 0, 768, 768);
        swiglu_kernel<<<37824, 256, 0, stream>>>(ug, s_u + (size_t)l * 3072,
                                                 s_v + (size_t)l * 3072, hidden);
        // down, split-K = 4
        gemm_bt<<<dim3(6, 25, 4), 256, 0, stream>>>(hidden, 3072, wd, wd, wd,
                                                    6, 0, ug, 768, PSTR, 768, 3072);
        residual_cos<<<3152, 256, 0, stream>>>(ug, 4, PSTR, alM + (size_t)l * 768, h, hb);

        if (l == 10) layernorm_out<<<3136, 256, 0, stream>>>(h, fcw, fcb, out);
        if (l == 11) layernorm_out<<<3136, 256, 0, stream>>>(h, fcw, fcb, out + 2408448);
    }
}

// Round 3
// 2622.876 us; speedup vs baseline: 1.1944x; 1.1944x over previous
//
#include <hip/hip_runtime.h>
#include <hip/hip_bf16.h>
#include <cstdint>
#include <cstddef>

typedef __hip_bfloat16 bf16;
typedef short bf16x8 __attribute__((ext_vector_type(8)));   // 8 bf16 (4 VGPRs)
typedef float f32x4 __attribute__((ext_vector_type(4)));

#define SQRT_E   27.712812921102035f   // sqrt(768)
#define ASCALE   (0.05f * 27.712812921102035f)
#define MPAD     3200                  // 3152 tokens padded to 25 * 128

__device__ __forceinline__ void load_lds16(const bf16* g, bf16* l) {
    __builtin_amdgcn_global_load_lds(
        (const __attribute__((address_space(1))) void*)g,
        (__attribute__((address_space(3))) void*)l, 16, 0, 0);
}

__device__ __forceinline__ float block_sum(float v, float* sbuf) {
#pragma unroll
    for (int m = 32; m >= 1; m >>= 1) v += __shfl_xor(v, m);
    __syncthreads();
    if ((threadIdx.x & 63) == 0) sbuf[threadIdx.x >> 6] = v;
    __syncthreads();
    return sbuf[0] + sbuf[1] + sbuf[2] + sbuf[3];
}

__device__ __forceinline__ void cvt8(const float* s, bf16* d) {
    float4 f0 = *(const float4*)s;
    float4 f1 = *(const float4*)(s + 4);
    bf16 t[8];
    t[0] = __float2bfloat16(f0.x); t[1] = __float2bfloat16(f0.y);
    t[2] = __float2bfloat16(f0.z); t[3] = __float2bfloat16(f0.w);
    t[4] = __float2bfloat16(f1.x); t[5] = __float2bfloat16(f1.y);
    t[6] = __float2bfloat16(f1.z); t[7] = __float2bfloat16(f1.w);
    *reinterpret_cast<uint4*>(d) = *reinterpret_cast<const uint4*>(t);
}

// ---------------- single-src f32 -> bf16 (patch weights) ----------------------
__global__ __launch_bounds__(256) void conv1_kernel(const float* __restrict__ src,
                                                    bf16* __restrict__ dst, int n8) {
    int idx = blockIdx.x * 256 + threadIdx.x;
    if (idx >= n8) return;
    cvt8(src + (size_t)idx * 8, dst + (size_t)idx * 8);
}

// ---------------- per-layer 7-weight f32 -> bf16 ------------------------------
// groups: wq,wk,wv,wo 73728 each; wu,wg,wd 294912 each; total 1179648
__global__ __launch_bounds__(256) void wconv_kernel(
    const float* __restrict__ wq, const float* __restrict__ wk,
    const float* __restrict__ wv, const float* __restrict__ wo,
    const float* __restrict__ wu, const float* __restrict__ wg,
    const float* __restrict__ wd, bf16* __restrict__ dst) {
    int idx = blockIdx.x * 256 + threadIdx.x;
    if (idx >= 1179648) return;
    const float* src;
    size_t off;
    if (idx < 294912) {
        int seg = idx / 73728, o = idx - seg * 73728;
        src = (seg == 0) ? wq : (seg == 1) ? wk : (seg == 2) ? wv : wo;
        off = (size_t)o * 8;
    } else {
        int i2 = idx - 294912;
        int seg = i2 / 294912, o = i2 - seg * 294912;
        src = (seg == 0) ? wu : (seg == 1) ? wg : wd;
        off = (size_t)o * 8;
    }
    cvt8(src + off, dst + (size_t)idx * 8);
}

// ---------------- im2col: x f32 [16,3,224,224] -> Apatch bf16 [3200][768] -----
__global__ __launch_bounds__(256) void im2col_kernel(const float* __restrict__ x,
                                                     bf16* __restrict__ A) {
    int idx = blockIdx.x * 256 + threadIdx.x;
    int row = idx / 768, col = idx - row * 768;
    if (row >= 3136) { A[idx] = __float2bfloat16(0.f); return; }
    int b = row / 196, pp = row - b * 196;
    int gy = pp / 14, gx = pp - gy * 14;
    int c = col >> 8, rem = col & 255, py = rem >> 4, px = rem & 15;
    A[idx] = __float2bfloat16(
        x[((size_t)(b * 3 + c) * 224 + gy * 16 + py) * 224 + gx * 16 + px]);
}

// ---------------- assemble h from tproj + cls + pos ---------------------------
__global__ __launch_bounds__(256) void assemble_kernel(
    const float* __restrict__ tproj, const float* __restrict__ pb,
    const float* __restrict__ cls, const float* __restrict__ pos,
    float* __restrict__ h, bf16* __restrict__ hb) {
    int row = blockIdx.x;
    int b = row / 197, n = row - b * 197;
#pragma unroll
    for (int i = 0; i < 3; i++) {
        int c = threadIdx.x + i * 256;
        float v;
        if (n == 0) v = cls[c] + pos[c];
        else v = tproj[(size_t)(b * 196 + n - 1) * 768 + c] + pb[c] + pos[(size_t)n * 768 + c];
        h[(size_t)row * 768 + c] = v;
        hb[(size_t)row * 768 + c] = __float2bfloat16(v);
    }
}

// ---------------- bf16 GEMM: C = A @ W^T (m97 structure, all-bf16 staging) ----
// grid.x = nSegs*tilesPerSeg; grid.y = M/128; grid.z = split-K part
__global__ __launch_bounds__(256) void gemm_bt(
    const bf16* __restrict__ A, int lda,
    const bf16* __restrict__ B0, const bf16* __restrict__ B1, const bf16* __restrict__ B2,
    int tilesPerSeg, int segColStride,
    void* __restrict__ Cv, int ldc, long long partStride,
    int Klen, int ldb, int outBf16) {
    __shared__ __align__(16) bf16 As[128 * 32];
    __shared__ __align__(16) bf16 Bs[128 * 32];
    const int tid = threadIdx.x;
    const int lane = tid & 63, wave = tid >> 6;
    const int wm = wave & 1, wn = wave >> 1;
    const int quad = lane >> 4, l16 = lane & 15;
    const int seg = blockIdx.x / tilesPerSeg;
    const int nt = blockIdx.x - seg * tilesPerSeg;
    const bf16* B = (seg == 0) ? B0 : (seg == 1 ? B1 : B2);
    const int row0 = blockIdx.y * 128;
    const int col0 = nt * 128;
    const long long kofs = (long long)blockIdx.z * Klen;
    const bf16* Ab = A + (size_t)row0 * lda + kofs;
    const bf16* Bb = B + (size_t)col0 * ldb + kofs;
    const long long cofs = (long long)blockIdx.z * partStride + (long long)seg * segColStride;

    f32x4 acc[4][4];
    f32x4 zero = {0.f, 0.f, 0.f, 0.f};
#pragma unroll
    for (int i = 0; i < 4; i++)
#pragma unroll
        for (int j = 0; j < 4; j++) acc[i][j] = zero;

    for (int k0 = 0; k0 < Klen; k0 += 32) {
#pragma unroll
        for (int it = 0; it < 2; ++it) {
            int cidx = it * 256 + tid;
            int r = cidx >> 2, cg = cidx & 3;
            load_lds16(Ab + (size_t)r * lda + k0 + cg * 8, As + cidx * 8);
            load_lds16(Bb + (size_t)r * ldb + k0 + cg * 8, Bs + cidx * 8);
        }
        __syncthreads();
        bf16x8 av[4], bv[4];
#pragma unroll
        for (int i = 0; i < 4; i++) {
            av[i] = *(const bf16x8*)(As + (wm * 64 + i * 16 + l16) * 32 + quad * 8);
            bv[i] = *(const bf16x8*)(Bs + (wn * 64 + i * 16 + l16) * 32 + quad * 8);
        }
#pragma unroll
        for (int i = 0; i < 4; i++)
#pragma unroll
            for (int j = 0; j < 4; j++)
                acc[i][j] = __builtin_amdgcn_mfma_f32_16x16x32_bf16(av[i], bv[j], acc[i][j], 0, 0, 0);
        __syncthreads();
    }
    if (outBf16) {
        bf16* Cb = (bf16*)Cv + cofs;
#pragma unroll
        for (int i = 0; i < 4; i++) {
            int rr = row0 + wm * 64 + i * 16 + quad * 4;
#pragma unroll
            for (int j = 0; j < 4; j++) {
                int cc = col0 + wn * 64 + j * 16 + l16;
#pragma unroll
                for (int r = 0; r < 4; r++)
                    Cb[(size_t)(rr + r) * ldc + cc] = __float2bfloat16(acc[i][j][r]);
            }
        }
    } else {
        float* Cb = (float*)Cv + cofs;
#pragma unroll
        for (int i = 0; i < 4; i++) {
            int rr = row0 + wm * 64 + i * 16 + quad * 4;
#pragma unroll
            for (int j = 0; j < 4; j++) {
                int cc = col0 + wn * 64 + j * 16 + l16;
#pragma unroll
                for (int r = 0; r < 4; r++)
                    Cb[(size_t)(rr + r) * ldc + cc] = acc[i][j][r];
            }
        }
    }
}

// ---------------- fused up/gate GEMM + SwiGLU -> hidden bf16 ------------------
// block: 128 rows x 64 hidden cols; dual accumulators (u and v)
__global__ __launch_bounds__(256) void gemm_upgate(
    const bf16* __restrict__ A, const bf16* __restrict__ Bu, const bf16* __restrict__ Bv,
    const float* __restrict__ su, const float* __restrict__ sv,
    bf16* __restrict__ H) {
    __shared__ __align__(16) bf16 As[128 * 32];
    __shared__ __align__(16) bf16 Bus[64 * 32];
    __shared__ __align__(16) bf16 Bvs[64 * 32];
    const int tid = threadIdx.x;
    const int lane = tid & 63, wave = tid >> 6;
    const int wm = wave & 1, wn = wave >> 1;     // wn in 0..1 -> 32-col half
    const int quad = lane >> 4, l16 = lane & 15;
    const int ct = blockIdx.x;                   // 0..47
    const int row0 = blockIdx.y * 128;
    const bf16* Ab = A + (size_t)row0 * 768;
    const bf16* Bub = Bu + (size_t)ct * 64 * 768;
    const bf16* Bvb = Bv + (size_t)ct * 64 * 768;

    f32x4 au[4][2], av_[4][2];
    f32x4 zero = {0.f, 0.f, 0.f, 0.f};
#pragma unroll
    for (int i = 0; i < 4; i++)
#pragma unroll
        for (int j = 0; j < 2; j++) { au[i][j] = zero; av_[i][j] = zero; }

    for (int k0 = 0; k0 < 768; k0 += 32) {
#pragma unroll
        for (int it = 0; it < 2; ++it) {
            int cidx = it * 256 + tid;
            int r = cidx >> 2, cg = cidx & 3;
            load_lds16(Ab + (size_t)r * 768 + k0 + cg * 8, As + cidx * 8);
        }
        {
            int r = tid >> 2, cg = tid & 3;
            load_lds16(Bub + (size_t)r * 768 + k0 + cg * 8, Bus + tid * 8);
            load_lds16(Bvb + (size_t)r * 768 + k0 + cg * 8, Bvs + tid * 8);
        }
        __syncthreads();
        bf16x8 a[4], bu[2], bv[2];
#pragma unroll
        for (int i = 0; i < 4; i++)
            a[i] = *(const bf16x8*)(As + (wm * 64 + i * 16 + l16) * 32 + quad * 8);
#pragma unroll
        for (int j = 0; j < 2; j++) {
            bu[j] = *(const bf16x8*)(Bus + (wn * 32 + j * 16 + l16) * 32 + quad * 8);
            bv[j] = *(const bf16x8*)(Bvs + (wn * 32 + j * 16 + l16) * 32 + quad * 8);
        }
#pragma unroll
        for (int i = 0; i < 4; i++)
#pragma unroll
            for (int j = 0; j < 2; j++) {
                au[i][j]  = __builtin_amdgcn_mfma_f32_16x16x32_bf16(a[i], bu[j], au[i][j], 0, 0, 0);
                av_[i][j] = __builtin_amdgcn_mfma_f32_16x16x32_bf16(a[i], bv[j], av_[i][j], 0, 0, 0);
            }
        __syncthreads();
    }
#pragma unroll
    for (int j = 0; j < 2; j++) {
        int cc = ct * 64 + wn * 32 + j * 16 + l16;
        float suc = su[cc];
        float svc = sv[cc] * SQRT_E;
#pragma unroll
        for (int i = 0; i < 4; i++) {
            int rr = row0 + wm * 64 + i * 16 + quad * 4;
#pragma unroll
            for (int r = 0; r < 4; r++) {
                float u = au[i][j][r] * suc;
                float v = av_[i][j][r] * svc;
                float sig = 1.f / (1.f + __expf(-v));
                H[(size_t)(rr + r) * 3072 + cc] = __float2bfloat16(u * v * sig);
            }
        }
    }
}

// ---------------- q/k cosine-norm + scale, build Q,K,VT bf16 ------------------
__global__ __launch_bounds__(256) void qk_norm_kernel(
    const bf16* __restrict__ qkv, const float* __restrict__ s_l,
    bf16* __restrict__ Q, bf16* __restrict__ K, bf16* __restrict__ VT) {
    int gw = blockIdx.x * 4 + (threadIdx.x >> 6);   // < 16*224*12
    int lane = threadIdx.x & 63;
    int h = gw % 12;
    int n = (gw / 12) % 224;
    int b = gw / (12 * 224);
    int bh = b * 12 + h;
    bf16 z = __float2bfloat16(0.f);
    if (n >= 208) { VT[((size_t)bh * 64 + lane) * 224 + n] = z; return; }
    if (n >= 197) {
        Q[((size_t)bh * 208 + n) * 64 + lane] = z;
        K[((size_t)bh * 208 + n) * 64 + lane] = z;
        VT[((size_t)bh * 64 + lane) * 224 + n] = z;
        return;
    }
    size_t row = (size_t)(b * 197 + n) * 2304;
    float q = __bfloat162float(qkv[row + h * 64 + lane]);
    float k = __bfloat162float(qkv[row + 768 + h * 64 + lane]);
    float v = __bfloat162float(qkv[row + 1536 + h * 64 + lane]);
    float qs = q * q, ks = k * k;
#pragma unroll
    for (int m = 32; m >= 1; m >>= 1) { qs += __shfl_xor(qs, m); ks += __shfl_xor(ks, m); }
    float s = s_l[h * 64 + lane] * SQRT_E;
    float qn = q / fmaxf(sqrtf(qs), 1e-6f) * s;
    float kn = k / fmaxf(sqrtf(ks), 1e-6f) * s;
    Q[((size_t)bh * 208 + n) * 64 + lane] = __float2bfloat16(qn);
    K[((size_t)bh * 208 + n) * 64 + lane] = __float2bfloat16(kn);
    VT[((size_t)bh * 64 + lane) * 224 + n] = __float2bfloat16(v);
}

// ---------------- attention: one wave per (b,h,q-tile) ------------------------
__global__ __launch_bounds__(64) void attn_kernel(
    const bf16* __restrict__ Q, const bf16* __restrict__ K,
    const bf16* __restrict__ VT, bf16* __restrict__ O) {
    __shared__ __align__(16) bf16 Ps[16 * 224];
    int lane = threadIdx.x;
    int quad = lane >> 4, l16 = lane & 15;
    int bh = blockIdx.x % 192;
    int qt = blockIdx.x / 192;
    int b = bh / 12, h = bh - b * 12;
    const bf16* Qb = Q + (size_t)bh * 208 * 64;
    const bf16* Kb = K + (size_t)bh * 208 * 64;
    const bf16* Vb = VT + (size_t)bh * 64 * 224;
    f32x4 zero = {0.f, 0.f, 0.f, 0.f};

    bf16x8 a0 = *(const bf16x8*)(Qb + (qt * 16 + l16) * 64 + quad * 8);
    bf16x8 a1 = *(const bf16x8*)(Qb + (qt * 16 + l16) * 64 + quad * 8 + 32);

    f32x4 lg[13];
#pragma unroll
    for (int kt = 0; kt < 13; kt++) {
        bf16x8 b0 = *(const bf16x8*)(Kb + (kt * 16 + l16) * 64 + quad * 8);
        bf16x8 b1 = *(const bf16x8*)(Kb + (kt * 16 + l16) * 64 + quad * 8 + 32);
        f32x4 c = zero;
        c = __builtin_amdgcn_mfma_f32_16x16x32_bf16(a0, b0, c, 0, 0, 0);
        c = __builtin_amdgcn_mfma_f32_16x16x32_bf16(a1, b1, c, 0, 0, 0);
        lg[kt] = c;
    }
    float mx[4] = {-3e38f, -3e38f, -3e38f, -3e38f};
#pragma unroll
    for (int kt = 0; kt < 13; kt++) {
        bool valid = (kt * 16 + l16) < 197;
#pragma unroll
        for (int r = 0; r < 4; r++) {
            float v = valid ? lg[kt][r] * 8.0f : -3e38f;
            lg[kt][r] = v;
            mx[r] = fmaxf(mx[r], v);
        }
    }
#pragma unroll
    for (int m = 1; m < 16; m <<= 1)
#pragma unroll
        for (int r = 0; r < 4; r++) mx[r] = fmaxf(mx[r], __shfl_xor(mx[r], m));
    float sm[4] = {0.f, 0.f, 0.f, 0.f};
#pragma unroll
    for (int kt = 0; kt < 13; kt++)
#pragma unroll
        for (int r = 0; r < 4; r++) {
            float p = __expf(lg[kt][r] - mx[r]);
            lg[kt][r] = p;
            sm[r] += p;
        }
#pragma unroll
    for (int m = 1; m < 16; m <<= 1)
#pragma unroll
        for (int r = 0; r < 4; r++) sm[r] += __shfl_xor(sm[r], m);
    float inv[4];
#pragma unroll
    for (int r = 0; r < 4; r++) inv[r] = 1.f / sm[r];
#pragma unroll
    for (int kt = 0; kt < 13; kt++)
#pragma unroll
        for (int r = 0; r < 4; r++)
            Ps[(quad * 4 + r) * 224 + kt * 16 + l16] = __float2bfloat16(lg[kt][r] * inv[r]);
#pragma unroll
    for (int r = 0; r < 4; r++)
        Ps[(quad * 4 + r) * 224 + 208 + l16] = __float2bfloat16(0.f);
    __syncthreads();
#pragma unroll
    for (int nt = 0; nt < 4; nt++) {
        f32x4 o = zero;
#pragma unroll
        for (int ks = 0; ks < 7; ks++) {
            bf16x8 pa = *(const bf16x8*)(Ps + l16 * 224 + ks * 32 + quad * 8);
            bf16x8 vb = *(const bf16x8*)(Vb + (nt * 16 + l16) * 224 + ks * 32 + quad * 8);
            o = __builtin_amdgcn_mfma_f32_16x16x32_bf16(pa, vb, o, 0, 0, 0);
        }
#pragma unroll
        for (int r = 0; r < 4; r++) {
            int tok = qt * 16 + quad * 4 + r;
            if (tok < 197)
                O[(size_t)(b * 197 + tok) * 768 + h * 64 + nt * 16 + l16] = __float2bfloat16(o[r]);
        }
    }
}

// ---------------- residual + cosine norms (sums split-K partials) -------------
__global__ __launch_bounds__(256) void residual_cos(
    const float* __restrict__ proj, int nParts, long long partStride,
    const float* __restrict__ alpha,
    float* __restrict__ h, bf16* __restrict__ hb) {
    __shared__ float sbuf[4];
    int row = blockIdx.x, tid = threadIdx.x;
    float p[3];
    float ss = 0.f;
#pragma unroll
    for (int i = 0; i < 3; i++) {
        int c = tid + i * 256;
        float v = 0.f;
        for (int pt = 0; pt < nParts; pt++) v += proj[(long long)pt * partStride + (size_t)row * 768 + c];
        p[i] = v;
        ss += v * v;
    }
    ss = block_sum(ss, sbuf);
    float inv1 = 1.f / fmaxf(sqrtf(ss), 1e-6f);
    float ss2 = 0.f;
#pragma unroll
    for (int i = 0; i < 3; i++) {
        int c = tid + i * 256;
        float hv = h[(size_t)row * 768 + c];
        float a = alpha[c] * ASCALE;
        float m = hv + a * (p[i] * inv1 - hv);
        p[i] = m;
        ss2 += m * m;
    }
    ss2 = block_sum(ss2, sbuf);
    float inv2 = 1.f / fmaxf(sqrtf(ss2), 1e-6f);
#pragma unroll
    for (int i = 0; i < 3; i++) {
        int c = tid + i * 256;
        float v = p[i] * inv2;
        h[(size_t)row * 768 + c] = v;
        hb[(size_t)row * 768 + c] = __float2bfloat16(v);
    }
}

// ---------------- layernorm of tokens 1..196 -> d_out (f32) -------------------
__global__ __launch_bounds__(256) void layernorm_out(
    const float* __restrict__ h, const float* __restrict__ w,
    const float* __restrict__ bia, float* __restrict__ out) {
    __shared__ float sbuf[4];
    int bi = blockIdx.x;
    int b = bi / 196, j = bi - b * 196;
    int row = b * 197 + j + 1;
    int tid = threadIdx.x;
    float xv[3];
    float s = 0.f;
#pragma unroll
    for (int i = 0; i < 3; i++) {
        xv[i] = h[(size_t)row * 768 + tid + i * 256];
        s += xv[i];
    }
    s = block_sum(s, sbuf);
    float mean = s * (1.f / 768.f);
    float s2 = 0.f;
#pragma unroll
    for (int i = 0; i < 3; i++) { float d = xv[i] - mean; s2 += d * d; }
    s2 = block_sum(s2, sbuf);
    float var = s2 * (1.f / 768.f);
    float invs = 1.f / sqrtf(var + 1e-6f);
#pragma unroll
    for (int i = 0; i < 3; i++) {
        int c = tid + i * 256;
        out[(size_t)bi * 768 + c] = (xv[i] - mean) * invs * w[c] + bia[c];
    }
}

extern "C" void kernel_launch(void* const* d_in, const int* in_sizes, int n_in,
                              void* d_out, int out_size, void* d_ws, size_t ws_size,
                              hipStream_t stream) {
    (void)in_sizes; (void)n_in; (void)out_size; (void)ws_size;
    const float* x      = (const float*)d_in[0];
    const float* patchw = (const float*)d_in[1];
    const float* patchb = (const float*)d_in[2];
    const float* cls    = (const float*)d_in[3];
    const float* pos    = (const float*)d_in[4];
    const float* Wq     = (const float*)d_in[5];
    const float* Wk     = (const float*)d_in[6];
    const float* Wv     = (const float*)d_in[7];
    const float* Wo     = (const float*)d_in[8];
    const float* s_qk   = (const float*)d_in[9];
    const float* Wup    = (const float*)d_in[10];
    const float* Wgate  = (const float*)d_in[11];
    const float* Wdown  = (const float*)d_in[12];
    const float* s_u    = (const float*)d_in[13];
    const float* s_v    = (const float*)d_in[14];
    const float* alA    = (const float*)d_in[15];
    const float* alM    = (const float*)d_in[16];
    const float* fcw    = (const float*)d_in[17];
    const float* fcb    = (const float*)d_in[18];
    float* out = (float*)d_out;

    char* ws = (char*)d_ws;
    size_t ofs = 0;
    auto alloc = [&](size_t bytes) -> void* {
        void* p = ws + ofs;
        ofs += (bytes + 255) & ~(size_t)255;
        return p;
    };
    // ~112 MB total, aliased (lifetimes disjoint within a layer):
    float* h      = (float*)alloc((size_t)MPAD * 768 * 4);        //  9.8 MB
    float* part   = (float*)alloc((size_t)4 * MPAD * 768 * 4);    // 39.3 MB: splitK partials | tproj | Q/K/VT
    bf16*  qkvb   = (bf16*)alloc((size_t)MPAD * 2304 * 2);        // 14.7 MB
    bf16*  hb     = (bf16*)alloc((size_t)MPAD * 768 * 2);         //  4.9 MB
    bf16*  attno  = (bf16*)alloc((size_t)MPAD * 768 * 2);         //  4.9 MB
    bf16*  hidden = (bf16*)alloc((size_t)MPAD * 3072 * 2);        // 19.7 MB (also Apatch)
    bf16*  wbf    = (bf16*)alloc((size_t)9437184 * 2);            // 18.9 MB per-layer bf16 weights

    float* tproj  = part;                        // pre-loop only
    bf16*  Qb     = (bf16*)part;                 // live qk_norm..attn only
    bf16*  Kb     = Qb + (size_t)192 * 208 * 64;
    bf16*  VTb    = Kb + (size_t)192 * 208 * 64;
    bf16*  Apatch = hidden;

    bf16* wqb = wbf;
    bf16* wkb = wbf + 589824;
    bf16* wvb = wbf + 1179648;
    bf16* wob = wbf + 1769472;
    bf16* wub = wbf + 2359296;
    bf16* wgb = wbf + 4718592;
    bf16* wdb = wbf + 7077888;

    const long long PSTR = (long long)MPAD * 768;
    const size_t EE = 768 * 768, FE = (size_t)3072 * 768;

    // ---- patch embed ----
    conv1_kernel<<<288, 256, 0, stream>>>(patchw, wqb, 73728);
    im2col_kernel<<<9600, 256, 0, stream>>>(x, Apatch);
    gemm_bt<<<dim3(6, 25, 1), 256, 0, stream>>>(Apatch, 768, wqb, wqb, wqb,
                                                6, 0, tproj, 768, 0, 768, 768, 0);
    assemble_kernel<<<3152, 256, 0, stream>>>(tproj, patchb, cls, pos, h, hb);

    for (int l = 0; l < 12; l++) {
        wconv_kernel<<<4608, 256, 0, stream>>>(Wq + (size_t)l * EE, Wk + (size_t)l * EE,
                                               Wv + (size_t)l * EE, Wo + (size_t)l * EE,
                                               Wup + (size_t)l * FE, Wgate + (size_t)l * FE,
                                               Wdown + (size_t)l * FE, wbf);
        // QKV (fused 3-segment GEMM, bf16 out)
        gemm_bt<<<dim3(18, 25, 1), 256, 0, stream>>>(hb, 768, wqb, wkb, wvb,
                                                     6, 768, qkvb, 2304, 0, 768, 768, 1);
        qk_norm_kernel<<<10752, 256, 0, stream>>>(qkvb, s_qk + (size_t)l * 768, Qb, Kb, VTb);
        attn_kernel<<<2496, 64, 0, stream>>>(Qb, Kb, VTb, attno);
        // O-proj, split-K = 2, f32 partials
        gemm_bt<<<dim3(6, 25, 2), 256, 0, stream>>>(attno, 768, wob, wob, wob,
                                                    6, 0, part, 768, PSTR, 384, 768, 0);
        residual_cos<<<3152, 256, 0, stream>>>(part, 2, PSTR, alA + (size_t)l * 768, h, hb);
        // fused up/gate + SwiGLU -> hidden bf16
        gemm_upgate<<<dim3(48, 25), 256, 0, stream>>>(hb, wub, wgb,
                                                      s_u + (size_t)l * 3072,
                                                      s_v + (size_t)l * 3072, hidden);
        // down, split-K = 4, f32 partials
        gemm_bt<<<dim3(6, 25, 4), 256, 0, stream>>>(hidden, 3072, wdb, wdb, wdb,
                                                    6, 0, part, 768, PSTR, 768, 3072, 0);
        residual_cos<<<3152, 256, 0, stream>>>(part, 4, PSTR, alM + (size_t)l * 768, h, hb);

        if (l == 10) layernorm_out<<<3136, 256, 0, stream>>>(h, fcw, fcb, out);
        if (l == 11) layernorm_out<<<3136, 256, 0, stream>>>(h, fcw, fcb, out + 2408448);
    }
}